// Round 10
// baseline (100.518 us; speedup 1.0000x reference)
//
#include <hip/hip_runtime.h>
#include <hip/hip_bf16.h>

// GraphAttentionLayer on MI355X. fp32 I/O, bf16 MFMA internally.
// e = LR(s1_i + s2_j), softmax_j, out = elu(attn @ Wh).
// Scale-free scores: q_ij = max(E_j, r_i*F_j); E=exp(s2-8), F=exp(a(s2-8)),
//   r_i = exp((a-1)(s1_i+8));  O_i = sum_j q Wh / sum_j q.
// K1: Wh MFMA -> tiled WhT [b][c:16][oct:32][f:128][jo:8] bf16 + s1,E,F.
// K3-v5 (R9-verified, 97.3us) + R10 XCD-locality remap: blk = jq*64 + g
//   (g = b*16+rgb) so a group's 8 sibling partials all land on XCD g%8's
//   L2 (8 groups x 512KB = 4MB/XCD). cvt_pk af-pack (R9).
// K4 (R10): blk = selw*64 + g (selw = wv,ntpair) -> k4 block for group g
//   lands on the XCD holding g's partials; pO/pl reads are local-L2 hits
//   if L2 survives the boundary. Output bitwise identical to R9.
// R6/R7 post-mortems: cross-block fused combine = HBM-bound by construction
//   (XCD L2 non-coherence); mono = latency-bound (114us). Both dead ends.

#define ALPHA 0.2f
#define NN 4096
#define FD 128

typedef __attribute__((ext_vector_type(8))) short s8v;     // 8 x bf16 raw bits
typedef __attribute__((ext_vector_type(4))) float f4v;
typedef __attribute__((ext_vector_type(2))) unsigned int u2v;
typedef __attribute__((ext_vector_type(4))) unsigned int u4v;

__device__ __forceinline__ unsigned short f2bf(float x) {  // round-half-up
  return (unsigned short)((__float_as_uint(x) + 0x8000u) >> 16);
}

// ---------------- K1: Wh + tiled WhT + s1/E/F (unchanged) ----------------
__global__ __launch_bounds__(256, 4) void k1_gemm(
    const float* __restrict__ h, const float* __restrict__ W,
    const float* __restrict__ a,
    unsigned short* __restrict__ WhTt,      // tiled [4][16][32][128][8] bf16
    float* __restrict__ s1g, float* __restrict__ Eg, float* __restrict__ Fg)
{
  __shared__ __align__(16) unsigned char wls[32768];
  const int tid = threadIdx.x;
  const int b = blockIdx.x >> 6;
  const int j0 = (blockIdx.x & 63) << 6;

#pragma unroll
  for (int it = 0; it < 16; ++it) {          // W -> swizzled bf16 W^T in LDS
    int cidx = it * 256 + tid;
    int i = cidx >> 5;
    int f0 = (cidx & 31) << 2;
    f4v v = *(const f4v*)(W + (size_t)cidx * 4);
#pragma unroll
    for (int e = 0; e < 4; ++e) {
      int f = f0 + e;
      int byte = f * 256 + (((i >> 3) ^ (f & 15)) << 4) + ((i & 7) << 1);
      *(unsigned short*)(wls + byte) = f2bf(v[e]);
    }
  }
  __syncthreads();

  const int w = tid >> 6, lane = tid & 63;
  const int quad = lane >> 4, lcol = lane & 15;
  const int jrow = j0 + 16 * w + lcol;

  f4v acc[8];
#pragma unroll
  for (int nt = 0; nt < 8; ++nt) acc[nt] = (f4v){0.f, 0.f, 0.f, 0.f};

#pragma unroll
  for (int kk = 0; kk < 4; ++kk) {
    const float* hp = h + (((size_t)(b * NN + jrow)) << 7) + (kk << 5) + (quad << 3);
    f4v v0 = *(const f4v*)hp;
    f4v v1 = *(const f4v*)(hp + 4);
    s8v af;
#pragma unroll
    for (int e = 0; e < 4; ++e) { af[e] = (short)f2bf(v0[e]); af[4+e] = (short)f2bf(v1[e]); }
#pragma unroll
    for (int nt = 0; nt < 8; ++nt) {
      int f = 16 * nt + lcol;
      int slot = ((kk << 2) + quad) ^ (f & 15);
      s8v bfr = *(const s8v*)(wls + (f << 8) + (slot << 4));
      acc[nt] = __builtin_amdgcn_mfma_f32_16x16x32_bf16(af, bfr, acc[nt], 0, 0, 0);
    }
  }

  float s1v[4] = {0,0,0,0}, s2v[4] = {0,0,0,0};
#pragma unroll
  for (int nt = 0; nt < 8; ++nt) {
    float a1 = a[16 * nt + lcol];
    float a2 = a[128 + 16 * nt + lcol];
#pragma unroll
    for (int r = 0; r < 4; ++r) { s1v[r] += acc[nt][r] * a1; s2v[r] += acc[nt][r] * a2; }
  }
#pragma unroll
  for (int r = 0; r < 4; ++r)
#pragma unroll
    for (int d = 1; d < 16; d <<= 1) {
      s1v[r] += __shfl_xor(s1v[r], d, 64);
      s2v[r] += __shfl_xor(s2v[r], d, 64);
    }
  if (lcol == 0) {
    int jb = b * NN + j0 + 16 * w + (quad << 2);
    *(f4v*)(s1g + jb) = (f4v){s1v[0], s1v[1], s1v[2], s1v[3]};
    f4v Ee, Ff;
#pragma unroll
    for (int r = 0; r < 4; ++r) {
      float d = s2v[r] - 8.0f;              // <= 0 given |s2| <= 8
      Ee[r] = __expf(d);
      Ff[r] = __expf(ALPHA * d);
    }
    *(f4v*)(Eg + jb) = Ee;
    *(f4v*)(Fg + jb) = Ff;
  }

  {
    const int c = j0 >> 8;
    const int octb = ((j0 & 255) >> 3) + 2 * w + (quad >> 1);
    const int eoff = (quad & 1) << 2;
#pragma unroll
    for (int nt = 0; nt < 8; ++nt) {
      int f = 16 * nt + lcol;
      unsigned u0 = __float_as_uint(acc[nt][0]) + 0x8000u;
      unsigned u1 = __float_as_uint(acc[nt][1]) + 0x8000u;
      unsigned u2 = __float_as_uint(acc[nt][2]) + 0x8000u;
      unsigned u3 = __float_as_uint(acc[nt][3]) + 0x8000u;
      u2v pk;
      pk[0] = (u0 >> 16) | (u1 & 0xFFFF0000u);
      pk[1] = (u2 >> 16) | (u3 & 0xFFFF0000u);
      size_t off = ((((size_t)(b * 16 + c) * 32 + octb) * 128 + f) << 3) + eoff;
      *(u2v*)(WhTt + off) = pk;
    }
  }
}

// ---------------- K3-v5: LDS-staged, 64 rows/wave, 2 blk/CU ---------------
// grid 512 x 256 thr. R10 remap: blk = jq*64 + g, g = b*16 + rgb.
// Wave w owns rows [rgb*256 + w*64, +64) (4 mt), j window [jq*512, +512)
// (16 ksteps x 32 j). LDS: buf0 [0,8K) | buf1 [8K,16K) | E [16K,18K) | F [18K,20K).
__global__ __launch_bounds__(256, 2) void k3_v5(
    const unsigned short* __restrict__ WhTt,
    const float* __restrict__ s1g,
    const float* __restrict__ Eg,
    const float* __restrict__ Fg,
    unsigned short* __restrict__ pO,        // [512][32768] bf16
    float* __restrict__ pl)                 // [512][256] f32
{
  __shared__ __align__(16) unsigned char smem[20480];
  const int tid = threadIdx.x;
  const int w = tid >> 6, lane = tid & 63;
  const int quad = lane >> 4, lcol = lane & 15;
  const int blk = blockIdx.x;
  const int jq = blk >> 6, g = blk & 63;    // R10: jq in HIGH bits -> siblings
  const int b = g >> 4, rgb = g & 15;       //      of a group share XCD g%8
  const int irow0 = rgb * 256 + w * 64;

  const unsigned short* whtb = WhTt + ((size_t)b << 19);
  const float* Egb = Eg + b * NN + (jq << 9);
  const float* Fgb = Fg + b * NN + (jq << 9);

  // E/F window: 512 + 512 floats, staged once
  if (tid < 128) {
    f4v v = *(const f4v*)(Egb + tid * 4);
    *(f4v*)(smem + 16384 + tid * 16) = v;
  } else {
    f4v v = *(const f4v*)(Fgb + (tid - 128) * 4);
    *(f4v*)(smem + 18432 + (tid - 128) * 16) = v;
  }

  float rr[4];
#pragma unroll
  for (int mt = 0; mt < 4; ++mt) {
    float x = s1g[b * NN + irow0 + 16 * mt + lcol] + 8.0f;
    rr[mt] = __expf((ALPHA - 1.0f) * x);    // <= 1 (x >= 0)
  }

  // B-tile for kstep s: 4 contiguous octets = 8KB (never crosses a c-tile)
  auto tilePtr = [&](int s) -> const unsigned short* {
    int og0 = (jq << 6) + (s << 2);
    return whtb + (((size_t)(og0 >> 5)) << 15) + ((og0 & 31) << 10);
  };
  {
    const unsigned short* tp = tilePtr(0);
    u4v t0 = *(const u4v*)(tp + tid * 8);          // bytes [tid*16, +16)
    u4v t1 = *(const u4v*)(tp + 2048 + tid * 8);   // second 4KB half
    *(u4v*)(smem + tid * 16) = t0;                 // bank-clean 16B stride
    *(u4v*)(smem + 4096 + tid * 16) = t1;
  }

  f4v acc[4][8], accL[4];
#pragma unroll
  for (int mt = 0; mt < 4; ++mt) {
    accL[mt] = (f4v){0.f, 0.f, 0.f, 0.f};
#pragma unroll
    for (int nt = 0; nt < 8; ++nt) acc[mt][nt] = (f4v){0.f, 0.f, 0.f, 0.f};
  }
  s8v ones;
  {
    short o = (lcol == 0) ? (short)0x3F80 : (short)0;
#pragma unroll
    for (int t = 0; t < 8; ++t) ones[t] = o;
  }

  const float* EFb = (const float*)(smem + 16384);

  for (int s = 0; s < 16; ++s) {            // 16 ksteps x 32 j
    __syncthreads();                        // tile s + EF resident; prev reads done
    u4v tn0, tn1;
    if (s < 15) {
      const unsigned short* tp = tilePtr(s + 1);
      tn0 = *(const u4v*)(tp + tid * 8);    // reg prefetch
      tn1 = *(const u4v*)(tp + 2048 + tid * 8);
    }
    const unsigned char* buf = smem + ((s & 1) << 13);

    const int jloc = (s << 5) + (quad << 3);
    f4v Ea0 = *(const f4v*)(EFb + jloc);
    f4v Ea1 = *(const f4v*)(EFb + jloc + 4);
    f4v Fa0 = *(const f4v*)(EFb + 512 + jloc);
    f4v Fa1 = *(const f4v*)(EFb + 512 + jloc + 4);
    float Ev[8] = {Ea0[0], Ea0[1], Ea0[2], Ea0[3], Ea1[0], Ea1[1], Ea1[2], Ea1[3]};
    float Fv[8] = {Fa0[0], Fa0[1], Fa0[2], Fa0[3], Fa1[0], Fa1[1], Fa1[2], Fa1[3]};

    s8v bfr[8];
#pragma unroll
    for (int nt = 0; nt < 8; ++nt) {        // B-frag: oct=quad, row f
      int f = (nt << 4) + lcol;
      bfr[nt] = *(const s8v*)(buf + (quad << 11) + (f << 4));
    }

    s8v af[4];
#pragma unroll
    for (int mt = 0; mt < 4; ++mt) {        // q = max(E, r*F) -> bf16 pairs
      float R = rr[mt];
      u4v pk4;
#pragma unroll
      for (int t = 0; t < 8; t += 2) {
        float q0 = fmaxf(Ev[t], R * Fv[t]);
        float q1 = fmaxf(Ev[t + 1], R * Fv[t + 1]);
        unsigned pr;
        asm("v_cvt_pk_bf16_f32 %0, %1, %2" : "=v"(pr) : "v"(q0), "v"(q1));
        pk4[t >> 1] = pr;                   // low16=bf16(q0), high16=bf16(q1)
      }
      af[mt] = __builtin_bit_cast(s8v, pk4);
    }
#pragma unroll
    for (int nt = 0; nt < 8; ++nt)
#pragma unroll
      for (int mt = 0; mt < 4; ++mt)
        acc[mt][nt] = __builtin_amdgcn_mfma_f32_16x16x32_bf16(af[mt], bfr[nt], acc[mt][nt], 0, 0, 0);
#pragma unroll
    for (int mt = 0; mt < 4; ++mt)
      accL[mt] = __builtin_amdgcn_mfma_f32_16x16x32_bf16(af[mt], ones, accL[mt], 0, 0, 0);

    if (s < 15) {                           // write prefetched tile s+1
      unsigned char* dst = smem + (((s + 1) & 1) << 13);
      *(u4v*)(dst + tid * 16) = tn0;
      *(u4v*)(dst + 4096 + tid * 16) = tn1;
    }
  }

  // partial stores, C-frag-native coalesced layout
  if (lcol == 0) {
#pragma unroll
    for (int mt = 0; mt < 4; ++mt)
#pragma unroll
      for (int r = 0; r < 4; ++r)
        pl[(size_t)blk * 256 + w * 64 + 16 * mt + (quad << 2) + r] = accL[mt][r];
  }
  unsigned short* po = pO + (size_t)blk * 32768;
#pragma unroll
  for (int mt = 0; mt < 4; ++mt)
#pragma unroll
    for (int nt = 0; nt < 8; ++nt) {
      unsigned u0 = __float_as_uint(acc[mt][nt][0]) + 0x8000u;
      unsigned u1 = __float_as_uint(acc[mt][nt][1]) + 0x8000u;
      unsigned u2 = __float_as_uint(acc[mt][nt][2]) + 0x8000u;
      unsigned u3 = __float_as_uint(acc[mt][nt][3]) + 0x8000u;
      u2v pk;
      pk[0] = (u0 >> 16) | (u1 & 0xFFFF0000u);
      pk[1] = (u2 >> 16) | (u3 & 0xFFFF0000u);
      int off = ((((w << 2) + mt) << 3) + nt) * 256 + (lane << 2);
      *(u2v*)(po + off) = pk;
    }
}

// ---------------- K4: 8-way combine + normalize + ELU, XCD-local ----------
// grid 1024 x 256 thr (4 blk/CU). R10: blk = selw*64 + g; selw=(wv<<2)|sel
// (sel = nt pair). Block for group g lands on XCD g%8 = where k3 wrote g's
// 8 partials (k3 blk = q*64 + g). Math/order identical to R9.
__global__ __launch_bounds__(256) void k4_comb(
    const unsigned short* __restrict__ pO, const float* __restrict__ pl,
    float* __restrict__ out)
{
  const int tid = threadIdx.x, blk = blockIdx.x;
  const int g = blk & 63, selw = blk >> 6;  // g -> XCD g%8 (matches k3)
  const int b = g >> 4, rgb = g & 15;
  const int wv = selw >> 2, sel = selw & 3;
  const int mt = tid >> 6, lane = tid & 63;
  const int quad = lane >> 4, lcol = lane & 15;

  float il[4];
#pragma unroll
  for (int r = 0; r < 4; ++r) {
    int rowloc = wv * 64 + 16 * mt + (quad << 2) + r;
    float l = 0.f;
#pragma unroll
    for (int q = 0; q < 8; ++q) l += pl[(size_t)((q << 6) + g) * 256 + rowloc];
    il[r] = 1.0f / l;
  }

  const size_t rowg0 = ((size_t)b * NN + rgb * 256 + wv * 64 + 16 * mt + (quad << 2));
#pragma unroll
  for (int ntl = 0; ntl < 2; ++ntl) {
    const int nt = (sel << 1) + ntl;
    const int off = ((((wv << 2) + mt) << 3) + nt) * 256 + (lane << 2);
    float s0 = 0.f, s1 = 0.f, s2 = 0.f, s3 = 0.f;
#pragma unroll
    for (int q = 0; q < 8; ++q) {
      u2v pk = *(const u2v*)(pO + (size_t)((q << 6) + g) * 32768 + off);
      s0 += __uint_as_float(pk[0] << 16);
      s1 += __uint_as_float(pk[0] & 0xFFFF0000u);
      s2 += __uint_as_float(pk[1] << 16);
      s3 += __uint_as_float(pk[1] & 0xFFFF0000u);
    }
    float v[4] = {s0 * il[0], s1 * il[1], s2 * il[2], s3 * il[3]};
#pragma unroll
    for (int r = 0; r < 4; ++r) {
      float x = v[r];
      x = x > 0.f ? x : (__expf(x) - 1.f);  // elu
      out[(rowg0 + r) * 128 + (nt << 4) + lcol] = x;
    }
  }
}

// ---------------- K3-mono (fallback only; R8: 114us latency-bound) --------
__global__ __launch_bounds__(512, 2) void k3_mono(
    const unsigned short* __restrict__ WhTt,
    const float* __restrict__ s1g,
    const float* __restrict__ Eg,
    const float* __restrict__ Fg,
    float* __restrict__ out)
{
  __shared__ __align__(16) unsigned char smem[33024];
  const int tid = threadIdx.x;
  const int kp = tid >> 6, lane = tid & 63;
  const int quad = lane >> 4, lcol = lane & 15;
  const int b = (blockIdx.x & 7) >> 1;
  const int i0 = ((((blockIdx.x & 1) << 5) | (blockIdx.x >> 3))) << 6;
  const int c0 = (blockIdx.x >> 3) & 15;
  const int oct = (kp << 2) + quad;

  float Ar[4], Br[4];
#pragma unroll
  for (int mt = 0; mt < 4; ++mt) {
    float x = s1g[b * NN + i0 + 16 * mt + lcol] + 8.0f;
    float m = fmaxf(x, ALPHA * x);
    Ar[mt] = __expf(x - m);
    Br[mt] = __expf(ALPHA * x - m);
  }

  f4v acc[4][8], accL[4];
#pragma unroll
  for (int mt = 0; mt < 4; ++mt) {
    accL[mt] = (f4v){0.f, 0.f, 0.f, 0.f};
#pragma unroll
    for (int nt = 0; nt < 8; ++nt) acc[mt][nt] = (f4v){0.f, 0.f, 0.f, 0.f};
  }
  s8v ones;
  {
    short o = (lcol == 0) ? (short)0x3F80 : (short)0;
#pragma unroll
    for (int t = 0; t < 8; ++t) ones[t] = o;
  }

  const unsigned short* whtb = WhTt + ((size_t)b << 19);
  const float* Egb = Eg + b * NN;
  const float* Fgb = Fg + b * NN;
  const int jw = oct << 3;

  f4v Ec0 = *(const f4v*)(Egb + (c0 << 8) + jw);
  f4v Ec1 = *(const f4v*)(Egb + (c0 << 8) + jw + 4);
  f4v Fc0 = *(const f4v*)(Fgb + (c0 << 8) + jw);
  f4v Fc1 = *(const f4v*)(Fgb + (c0 << 8) + jw + 4);

  for (int cc = 0; cc < 16; ++cc) {
    const int c = (cc + c0) & 15;
    const unsigned short* tile = whtb + ((size_t)c << 15) + (oct << 10);
    s8v bfr[8];
#pragma unroll
    for (int nt = 0; nt < 8; ++nt)
      bfr[nt] = *(const s8v*)(tile + (((nt << 4) + lcol) << 3));

    f4v En0, En1, Fn0, Fn1;
    if (cc < 15) {
      int jg = (((cc + 1 + c0) & 15) << 8) + jw;
      En0 = *(const f4v*)(Egb + jg); En1 = *(const f4v*)(Egb + jg + 4);
      Fn0 = *(const f4v*)(Fgb + jg); Fn1 = *(const f4v*)(Fgb + jg + 4);
    }

    float Ev[8] = {Ec0[0], Ec0[1], Ec0[2], Ec0[3], Ec1[0], Ec1[1], Ec1[2], Ec1[3]};
    float Fv[8] = {Fc0[0], Fc0[1], Fc0[2], Fc0[3], Fc1[0], Fc1[1], Fc1[2], Fc1[3]};

    s8v af[4];
#pragma unroll
    for (int mt = 0; mt < 4; ++mt) {
      float A = Ar[mt], Bc = Br[mt];
      u4v pk4;
#pragma unroll
      for (int t = 0; t < 8; t += 2) {
        float p0 = fmaxf(A * Ev[t], Bc * Fv[t]);
        float p1 = fmaxf(A * Ev[t + 1], Bc * Fv[t + 1]);
        unsigned u0 = __float_as_uint(p0) + 0x8000u;
        unsigned u1 = __float_as_uint(p1) + 0x8000u;
        pk4[t >> 1] = __builtin_amdgcn_perm(u1, u0, 0x07060302);
      }
      af[mt] = __builtin_bit_cast(s8v, pk4);
    }
#pragma unroll
    for (int nt = 0; nt < 8; ++nt)
#pragma unroll
      for (int mt = 0; mt < 4; ++mt)
        acc[mt][nt] = __builtin_amdgcn_mfma_f32_16x16x32_bf16(af[mt], bfr[nt], acc[mt][nt], 0, 0, 0);
#pragma unroll
    for (int mt = 0; mt < 4; ++mt)
      accL[mt] = __builtin_amdgcn_mfma_f32_16x16x32_bf16(af[mt], ones, accL[mt], 0, 0, 0);

    Ec0 = En0; Ec1 = En1; Fc0 = Fn0; Fc1 = Fn1;
  }

  float* hsum = (float*)smem;
  float* l_red = (float*)(smem + 32768);
#pragma unroll
  for (int t = 0; t < 4; ++t)
    *(f4v*)(hsum + tid * 16 + t * 4) = (f4v){0.f, 0.f, 0.f, 0.f};
  if (tid < 64) l_red[tid] = 0.f;
  __syncthreads();

#pragma unroll
  for (int mt = 0; mt < 4; ++mt) {
    if (lcol == 0) {
#pragma unroll
      for (int r = 0; r < 4; ++r)
        atomicAdd(&l_red[16 * mt + (quad << 2) + r], accL[mt][r]);
    }
#pragma unroll
    for (int nt = 0; nt < 8; ++nt)
#pragma unroll
      for (int r = 0; r < 4; ++r) {
        int row = 16 * mt + (quad << 2) + r;
        int f = (nt << 4) + lcol;
        int fx = (f + (quad << 3)) & 127;
        atomicAdd(&hsum[(row << 7) + fx], acc[mt][nt][r]);
      }
  }
  __syncthreads();

  {
    int r = tid >> 3;
    int f0 = (tid & 7) << 4;
    int off = ((r >> 2) & 3) << 3;
    float il = 1.0f / l_red[r];
    size_t o = (((size_t)b * NN + i0 + r) << 7) + f0;
#pragma unroll
    for (int t = 0; t < 4; ++t) {
      int fx = (f0 + 4 * t + off) & 127;
      f4v v = *(const f4v*)(hsum + (r << 7) + fx);
      f4v ov;
#pragma unroll
      for (int e = 0; e < 4; ++e) {
        float x = v[e] * il;
        ov[e] = x > 0.f ? x : (__expf(x) - 1.f);
      }
      *(f4v*)(out + o + 4 * t) = ov;
    }
  }
}

extern "C" void kernel_launch(void* const* d_in, const int* in_sizes, int n_in,
                              void* d_out, int out_size, void* d_ws, size_t ws_size,
                              hipStream_t stream) {
  const float* h = (const float*)d_in[0];
  const float* W = (const float*)d_in[1];
  const float* a = (const float*)d_in[2];
  float* out = (float*)d_out;
  unsigned char* ws = (unsigned char*)d_ws;

  unsigned short* WhTt = (unsigned short*)ws;             // 4 MB tiled bf16
  float* s1g = (float*)(ws + 4194304);                    // 64 KB
  float* Eg  = (float*)(ws + 4259840);                    // 64 KB
  float* Fg  = (float*)(ws + 4325376);                    // 64 KB
  unsigned short* pO = (unsigned short*)(ws + 4390912);   // 33.6 MB bf16
  float* pl = (float*)(ws + 37945344);                    // 512 KB
  const size_t NEED_SPLIT = 38469632;
  const size_t NEED_MONO = 4390912;
  if (ws_size < NEED_MONO) return;  // clean absmax-fail => ws too small

  hipLaunchKernelGGL(k1_gemm, dim3(256), dim3(256), 0, stream,
                     h, W, a, WhTt, s1g, Eg, Fg);
  if (ws_size >= NEED_SPLIT) {
    hipLaunchKernelGGL(k3_v5, dim3(512), dim3(256), 0, stream,
                       WhTt, s1g, Eg, Fg, pO, pl);
    hipLaunchKernelGGL(k4_comb, dim3(1024), dim3(256), 0, stream,
                       pO, pl, out);
  } else {
    hipLaunchKernelGGL(k3_mono, dim3(256), dim3(512), 0, stream,
                       WhTt, s1g, Eg, Fg, out);
  }
}

// Round 11
// 98.141 us; speedup vs baseline: 1.0242x; 1.0242x over previous
//
#include <hip/hip_runtime.h>
#include <hip/hip_bf16.h>

// GraphAttentionLayer on MI355X. fp32 I/O, bf16 MFMA internally.
// e = LR(s1_i + s2_j), softmax_j, out = elu(attn @ Wh).
// Scale-free scores: q_ij = max(E_j, r_i*F_j); E=exp(s2-8), F=exp(a(s2-8)),
//   r_i = exp((a-1)(s1_i+8));  O_i = sum_j q Wh / sum_j q.
// K1: Wh MFMA -> tiled WhT [b][c:16][oct:32][f:128][jo:8] bf16 + s1,E,F.
// K3-v5 (R9 mapping RESTORED: blk = b*128+rgb*8+jq -> blk%8=jq gives each
//   XCD one 512KB B-panel; R10's g-major remap cost 3.2us by breaking this.
//   pO locality across the boundary is L3-level, placement-indifferent.)
//   cvt_pk af-pack (R9). R11: PAIRED pO layout — nt pair interleaved at
//   lane*8+(nt&1)*4 so k3 stores 16B and k4 loads dwordx4 (1KB/wave).
// K4: 1024 blocks x 256 thr (R9), paired 16B reads. Bitwise = R9 output.
// Dead ends (post-mortems): coop grid.sync (R4, ~220us); cross-block fused
//   combine (R6, device-scope release -> HBM); mono 1blk/CU (R8, 114us).

#define ALPHA 0.2f
#define NN 4096
#define FD 128

typedef __attribute__((ext_vector_type(8))) short s8v;     // 8 x bf16 raw bits
typedef __attribute__((ext_vector_type(4))) float f4v;
typedef __attribute__((ext_vector_type(2))) unsigned int u2v;
typedef __attribute__((ext_vector_type(4))) unsigned int u4v;

__device__ __forceinline__ unsigned short f2bf(float x) {  // round-half-up
  return (unsigned short)((__float_as_uint(x) + 0x8000u) >> 16);
}

// ---------------- K1: Wh + tiled WhT + s1/E/F (unchanged) ----------------
__global__ __launch_bounds__(256, 4) void k1_gemm(
    const float* __restrict__ h, const float* __restrict__ W,
    const float* __restrict__ a,
    unsigned short* __restrict__ WhTt,      // tiled [4][16][32][128][8] bf16
    float* __restrict__ s1g, float* __restrict__ Eg, float* __restrict__ Fg)
{
  __shared__ __align__(16) unsigned char wls[32768];
  const int tid = threadIdx.x;
  const int b = blockIdx.x >> 6;
  const int j0 = (blockIdx.x & 63) << 6;

#pragma unroll
  for (int it = 0; it < 16; ++it) {          // W -> swizzled bf16 W^T in LDS
    int cidx = it * 256 + tid;
    int i = cidx >> 5;
    int f0 = (cidx & 31) << 2;
    f4v v = *(const f4v*)(W + (size_t)cidx * 4);
#pragma unroll
    for (int e = 0; e < 4; ++e) {
      int f = f0 + e;
      int byte = f * 256 + (((i >> 3) ^ (f & 15)) << 4) + ((i & 7) << 1);
      *(unsigned short*)(wls + byte) = f2bf(v[e]);
    }
  }
  __syncthreads();

  const int w = tid >> 6, lane = tid & 63;
  const int quad = lane >> 4, lcol = lane & 15;
  const int jrow = j0 + 16 * w + lcol;

  f4v acc[8];
#pragma unroll
  for (int nt = 0; nt < 8; ++nt) acc[nt] = (f4v){0.f, 0.f, 0.f, 0.f};

#pragma unroll
  for (int kk = 0; kk < 4; ++kk) {
    const float* hp = h + (((size_t)(b * NN + jrow)) << 7) + (kk << 5) + (quad << 3);
    f4v v0 = *(const f4v*)hp;
    f4v v1 = *(const f4v*)(hp + 4);
    s8v af;
#pragma unroll
    for (int e = 0; e < 4; ++e) { af[e] = (short)f2bf(v0[e]); af[4+e] = (short)f2bf(v1[e]); }
#pragma unroll
    for (int nt = 0; nt < 8; ++nt) {
      int f = 16 * nt + lcol;
      int slot = ((kk << 2) + quad) ^ (f & 15);
      s8v bfr = *(const s8v*)(wls + (f << 8) + (slot << 4));
      acc[nt] = __builtin_amdgcn_mfma_f32_16x16x32_bf16(af, bfr, acc[nt], 0, 0, 0);
    }
  }

  float s1v[4] = {0,0,0,0}, s2v[4] = {0,0,0,0};
#pragma unroll
  for (int nt = 0; nt < 8; ++nt) {
    float a1 = a[16 * nt + lcol];
    float a2 = a[128 + 16 * nt + lcol];
#pragma unroll
    for (int r = 0; r < 4; ++r) { s1v[r] += acc[nt][r] * a1; s2v[r] += acc[nt][r] * a2; }
  }
#pragma unroll
  for (int r = 0; r < 4; ++r)
#pragma unroll
    for (int d = 1; d < 16; d <<= 1) {
      s1v[r] += __shfl_xor(s1v[r], d, 64);
      s2v[r] += __shfl_xor(s2v[r], d, 64);
    }
  if (lcol == 0) {
    int jb = b * NN + j0 + 16 * w + (quad << 2);
    *(f4v*)(s1g + jb) = (f4v){s1v[0], s1v[1], s1v[2], s1v[3]};
    f4v Ee, Ff;
#pragma unroll
    for (int r = 0; r < 4; ++r) {
      float d = s2v[r] - 8.0f;              // <= 0 given |s2| <= 8
      Ee[r] = __expf(d);
      Ff[r] = __expf(ALPHA * d);
    }
    *(f4v*)(Eg + jb) = Ee;
    *(f4v*)(Fg + jb) = Ff;
  }

  {
    const int c = j0 >> 8;
    const int octb = ((j0 & 255) >> 3) + 2 * w + (quad >> 1);
    const int eoff = (quad & 1) << 2;
#pragma unroll
    for (int nt = 0; nt < 8; ++nt) {
      int f = 16 * nt + lcol;
      unsigned u0 = __float_as_uint(acc[nt][0]) + 0x8000u;
      unsigned u1 = __float_as_uint(acc[nt][1]) + 0x8000u;
      unsigned u2 = __float_as_uint(acc[nt][2]) + 0x8000u;
      unsigned u3 = __float_as_uint(acc[nt][3]) + 0x8000u;
      u2v pk;
      pk[0] = (u0 >> 16) | (u1 & 0xFFFF0000u);
      pk[1] = (u2 >> 16) | (u3 & 0xFFFF0000u);
      size_t off = ((((size_t)(b * 16 + c) * 32 + octb) * 128 + f) << 3) + eoff;
      *(u2v*)(WhTt + off) = pk;
    }
  }
}

// ---------------- K3-v5: LDS-staged, 64 rows/wave, 2 blk/CU ---------------
// grid 512 x 256 thr. blk: b=blk>>7, rgb=(blk>>3)&15, jq=blk&7 (R9 mapping).
// Wave w owns rows [rgb*256 + w*64, +64) (4 mt), j window [jq*512, +512)
// (16 ksteps x 32 j). LDS: buf0 [0,8K) | buf1 [8K,16K) | E [16K,18K) | F [18K,20K).
__global__ __launch_bounds__(256, 2) void k3_v5(
    const unsigned short* __restrict__ WhTt,
    const float* __restrict__ s1g,
    const float* __restrict__ Eg,
    const float* __restrict__ Fg,
    unsigned short* __restrict__ pO,        // [512][32768] bf16, paired layout
    float* __restrict__ pl)                 // [512][256] f32
{
  __shared__ __align__(16) unsigned char smem[20480];
  const int tid = threadIdx.x;
  const int w = tid >> 6, lane = tid & 63;
  const int quad = lane >> 4, lcol = lane & 15;
  const int blk = blockIdx.x;
  const int b = blk >> 7, rgb = (blk >> 3) & 15, jq = blk & 7;
  const int irow0 = rgb * 256 + w * 64;

  const unsigned short* whtb = WhTt + ((size_t)b << 19);
  const float* Egb = Eg + b * NN + (jq << 9);
  const float* Fgb = Fg + b * NN + (jq << 9);

  // E/F window: 512 + 512 floats, staged once
  if (tid < 128) {
    f4v v = *(const f4v*)(Egb + tid * 4);
    *(f4v*)(smem + 16384 + tid * 16) = v;
  } else {
    f4v v = *(const f4v*)(Fgb + (tid - 128) * 4);
    *(f4v*)(smem + 18432 + (tid - 128) * 16) = v;
  }

  float rr[4];
#pragma unroll
  for (int mt = 0; mt < 4; ++mt) {
    float x = s1g[b * NN + irow0 + 16 * mt + lcol] + 8.0f;
    rr[mt] = __expf((ALPHA - 1.0f) * x);    // <= 1 (x >= 0)
  }

  // B-tile for kstep s: 4 contiguous octets = 8KB (never crosses a c-tile)
  auto tilePtr = [&](int s) -> const unsigned short* {
    int og0 = (jq << 6) + (s << 2);
    return whtb + (((size_t)(og0 >> 5)) << 15) + ((og0 & 31) << 10);
  };
  {
    const unsigned short* tp = tilePtr(0);
    u4v t0 = *(const u4v*)(tp + tid * 8);          // bytes [tid*16, +16)
    u4v t1 = *(const u4v*)(tp + 2048 + tid * 8);   // second 4KB half
    *(u4v*)(smem + tid * 16) = t0;                 // bank-clean 16B stride
    *(u4v*)(smem + 4096 + tid * 16) = t1;
  }

  f4v acc[4][8], accL[4];
#pragma unroll
  for (int mt = 0; mt < 4; ++mt) {
    accL[mt] = (f4v){0.f, 0.f, 0.f, 0.f};
#pragma unroll
    for (int nt = 0; nt < 8; ++nt) acc[mt][nt] = (f4v){0.f, 0.f, 0.f, 0.f};
  }
  s8v ones;
  {
    short o = (lcol == 0) ? (short)0x3F80 : (short)0;
#pragma unroll
    for (int t = 0; t < 8; ++t) ones[t] = o;
  }

  const float* EFb = (const float*)(smem + 16384);

  for (int s = 0; s < 16; ++s) {            // 16 ksteps x 32 j
    __syncthreads();                        // tile s + EF resident; prev reads done
    u4v tn0, tn1;
    if (s < 15) {
      const unsigned short* tp = tilePtr(s + 1);
      tn0 = *(const u4v*)(tp + tid * 8);    // reg prefetch
      tn1 = *(const u4v*)(tp + 2048 + tid * 8);
    }
    const unsigned char* buf = smem + ((s & 1) << 13);

    const int jloc = (s << 5) + (quad << 3);
    f4v Ea0 = *(const f4v*)(EFb + jloc);
    f4v Ea1 = *(const f4v*)(EFb + jloc + 4);
    f4v Fa0 = *(const f4v*)(EFb + 512 + jloc);
    f4v Fa1 = *(const f4v*)(EFb + 512 + jloc + 4);
    float Ev[8] = {Ea0[0], Ea0[1], Ea0[2], Ea0[3], Ea1[0], Ea1[1], Ea1[2], Ea1[3]};
    float Fv[8] = {Fa0[0], Fa0[1], Fa0[2], Fa0[3], Fa1[0], Fa1[1], Fa1[2], Fa1[3]};

    s8v bfr[8];
#pragma unroll
    for (int nt = 0; nt < 8; ++nt) {        // B-frag: oct=quad, row f
      int f = (nt << 4) + lcol;
      bfr[nt] = *(const s8v*)(buf + (quad << 11) + (f << 4));
    }

    s8v af[4];
#pragma unroll
    for (int mt = 0; mt < 4; ++mt) {        // q = max(E, r*F) -> bf16 pairs
      float R = rr[mt];
      u4v pk4;
#pragma unroll
      for (int t = 0; t < 8; t += 2) {
        float q0 = fmaxf(Ev[t], R * Fv[t]);
        float q1 = fmaxf(Ev[t + 1], R * Fv[t + 1]);
        unsigned pr;
        asm("v_cvt_pk_bf16_f32 %0, %1, %2" : "=v"(pr) : "v"(q0), "v"(q1));
        pk4[t >> 1] = pr;                   // low16=bf16(q0), high16=bf16(q1)
      }
      af[mt] = __builtin_bit_cast(s8v, pk4);
    }
#pragma unroll
    for (int nt = 0; nt < 8; ++nt)
#pragma unroll
      for (int mt = 0; mt < 4; ++mt)
        acc[mt][nt] = __builtin_amdgcn_mfma_f32_16x16x32_bf16(af[mt], bfr[nt], acc[mt][nt], 0, 0, 0);
#pragma unroll
    for (int mt = 0; mt < 4; ++mt)
      accL[mt] = __builtin_amdgcn_mfma_f32_16x16x32_bf16(af[mt], ones, accL[mt], 0, 0, 0);

    if (s < 15) {                           // write prefetched tile s+1
      unsigned char* dst = smem + (((s + 1) & 1) << 13);
      *(u4v*)(dst + tid * 16) = tn0;
      *(u4v*)(dst + 4096 + tid * 16) = tn1;
    }
  }

  // partial stores, PAIRED layout (R11): nt pair interleaved -> 16B stores
  if (lcol == 0) {
#pragma unroll
    for (int mt = 0; mt < 4; ++mt)
#pragma unroll
      for (int r = 0; r < 4; ++r)
        pl[(size_t)blk * 256 + w * 64 + 16 * mt + (quad << 2) + r] = accL[mt][r];
  }
  unsigned short* po = pO + (size_t)blk * 32768;
#pragma unroll
  for (int mt = 0; mt < 4; ++mt)
#pragma unroll
    for (int pr = 0; pr < 4; ++pr) {
      u4v pk;
      {
        unsigned u0 = __float_as_uint(acc[mt][2 * pr][0]) + 0x8000u;
        unsigned u1 = __float_as_uint(acc[mt][2 * pr][1]) + 0x8000u;
        unsigned u2 = __float_as_uint(acc[mt][2 * pr][2]) + 0x8000u;
        unsigned u3 = __float_as_uint(acc[mt][2 * pr][3]) + 0x8000u;
        pk[0] = (u0 >> 16) | (u1 & 0xFFFF0000u);
        pk[1] = (u2 >> 16) | (u3 & 0xFFFF0000u);
      }
      {
        unsigned u0 = __float_as_uint(acc[mt][2 * pr + 1][0]) + 0x8000u;
        unsigned u1 = __float_as_uint(acc[mt][2 * pr + 1][1]) + 0x8000u;
        unsigned u2 = __float_as_uint(acc[mt][2 * pr + 1][2]) + 0x8000u;
        unsigned u3 = __float_as_uint(acc[mt][2 * pr + 1][3]) + 0x8000u;
        pk[2] = (u0 >> 16) | (u1 & 0xFFFF0000u);
        pk[3] = (u2 >> 16) | (u3 & 0xFFFF0000u);
      }
      int off = ((((w << 2) + mt) << 2) + pr) * 512 + (lane << 3);
      *(u4v*)(po + off) = pk;
    }
}

// ---------------- K4: 8-way combine + normalize + ELU, paired reads -------
// grid 1024 x 256 thr (4 blk/CU, R9 mapping). b=blk>>8; chunk=(blk>>2)&63;
// sel=blk&3 picks nt pair {2sel,2sel+1}; one dwordx4 per q covers both.
__global__ __launch_bounds__(256) void k4_comb(
    const unsigned short* __restrict__ pO, const float* __restrict__ pl,
    float* __restrict__ out)
{
  const int tid = threadIdx.x, blk = blockIdx.x;
  const int b = blk >> 8, chunk = (blk >> 2) & 63, sel = blk & 3;
  const int rgb = chunk >> 2, wv = chunk & 3;
  const int mt = tid >> 6, lane = tid & 63;
  const int quad = lane >> 4, lcol = lane & 15;
  const int kb = (b << 7) | (rgb << 3);     // k3 blk of q=0

  float il[4];
#pragma unroll
  for (int r = 0; r < 4; ++r) {
    int rowloc = wv * 64 + 16 * mt + (quad << 2) + r;
    float l = 0.f;
#pragma unroll
    for (int q = 0; q < 8; ++q) l += pl[(size_t)(kb + q) * 256 + rowloc];
    il[r] = 1.0f / l;
  }

  const size_t rowg0 = ((size_t)b * NN + rgb * 256 + wv * 64 + 16 * mt + (quad << 2));
  const int off = ((((wv << 2) + mt) << 2) + sel) * 512 + (lane << 3);
  float se[4] = {0.f, 0.f, 0.f, 0.f}, so[4] = {0.f, 0.f, 0.f, 0.f};
#pragma unroll
  for (int q = 0; q < 8; ++q) {
    u4v pk = *(const u4v*)(pO + (size_t)(kb + q) * 32768 + off);
    se[0] += __uint_as_float(pk[0] << 16);
    se[1] += __uint_as_float(pk[0] & 0xFFFF0000u);
    se[2] += __uint_as_float(pk[1] << 16);
    se[3] += __uint_as_float(pk[1] & 0xFFFF0000u);
    so[0] += __uint_as_float(pk[2] << 16);
    so[1] += __uint_as_float(pk[2] & 0xFFFF0000u);
    so[2] += __uint_as_float(pk[3] << 16);
    so[3] += __uint_as_float(pk[3] & 0xFFFF0000u);
  }
#pragma unroll
  for (int half = 0; half < 2; ++half) {
    const int nt = (sel << 1) + half;
    const float* sv = half ? so : se;
#pragma unroll
    for (int r = 0; r < 4; ++r) {
      float x = sv[r] * il[r];
      x = x > 0.f ? x : (__expf(x) - 1.f);  // elu
      out[(rowg0 + r) * 128 + (nt << 4) + lcol] = x;
    }
  }
}

// ---------------- K3-mono (fallback only; R8: 114us latency-bound) --------
__global__ __launch_bounds__(512, 2) void k3_mono(
    const unsigned short* __restrict__ WhTt,
    const float* __restrict__ s1g,
    const float* __restrict__ Eg,
    const float* __restrict__ Fg,
    float* __restrict__ out)
{
  __shared__ __align__(16) unsigned char smem[33024];
  const int tid = threadIdx.x;
  const int kp = tid >> 6, lane = tid & 63;
  const int quad = lane >> 4, lcol = lane & 15;
  const int b = (blockIdx.x & 7) >> 1;
  const int i0 = ((((blockIdx.x & 1) << 5) | (blockIdx.x >> 3))) << 6;
  const int c0 = (blockIdx.x >> 3) & 15;
  const int oct = (kp << 2) + quad;

  float Ar[4], Br[4];
#pragma unroll
  for (int mt = 0; mt < 4; ++mt) {
    float x = s1g[b * NN + i0 + 16 * mt + lcol] + 8.0f;
    float m = fmaxf(x, ALPHA * x);
    Ar[mt] = __expf(x - m);
    Br[mt] = __expf(ALPHA * x - m);
  }

  f4v acc[4][8], accL[4];
#pragma unroll
  for (int mt = 0; mt < 4; ++mt) {
    accL[mt] = (f4v){0.f, 0.f, 0.f, 0.f};
#pragma unroll
    for (int nt = 0; nt < 8; ++nt) acc[mt][nt] = (f4v){0.f, 0.f, 0.f, 0.f};
  }
  s8v ones;
  {
    short o = (lcol == 0) ? (short)0x3F80 : (short)0;
#pragma unroll
    for (int t = 0; t < 8; ++t) ones[t] = o;
  }

  const unsigned short* whtb = WhTt + ((size_t)b << 19);
  const float* Egb = Eg + b * NN;
  const float* Fgb = Fg + b * NN;
  const int jw = oct << 3;

  f4v Ec0 = *(const f4v*)(Egb + (c0 << 8) + jw);
  f4v Ec1 = *(const f4v*)(Egb + (c0 << 8) + jw + 4);
  f4v Fc0 = *(const f4v*)(Fgb + (c0 << 8) + jw);
  f4v Fc1 = *(const f4v*)(Fgb + (c0 << 8) + jw + 4);

  for (int cc = 0; cc < 16; ++cc) {
    const int c = (cc + c0) & 15;
    const unsigned short* tile = whtb + ((size_t)c << 15) + (oct << 10);
    s8v bfr[8];
#pragma unroll
    for (int nt = 0; nt < 8; ++nt)
      bfr[nt] = *(const s8v*)(tile + (((nt << 4) + lcol) << 3));

    f4v En0, En1, Fn0, Fn1;
    if (cc < 15) {
      int jg = (((cc + 1 + c0) & 15) << 8) + jw;
      En0 = *(const f4v*)(Egb + jg); En1 = *(const f4v*)(Egb + jg + 4);
      Fn0 = *(const f4v*)(Fgb + jg); Fn1 = *(const f4v*)(Fgb + jg + 4);
    }

    float Ev[8] = {Ec0[0], Ec0[1], Ec0[2], Ec0[3], Ec1[0], Ec1[1], Ec1[2], Ec1[3]};
    float Fv[8] = {Fc0[0], Fc0[1], Fc0[2], Fc0[3], Fc1[0], Fc1[1], Fc1[2], Fc1[3]};

    s8v af[4];
#pragma unroll
    for (int mt = 0; mt < 4; ++mt) {
      float A = Ar[mt], Bc = Br[mt];
      u4v pk4;
#pragma unroll
      for (int t = 0; t < 8; t += 2) {
        float p0 = fmaxf(A * Ev[t], Bc * Fv[t]);
        float p1 = fmaxf(A * Ev[t + 1], Bc * Fv[t + 1]);
        unsigned u0 = __float_as_uint(p0) + 0x8000u;
        unsigned u1 = __float_as_uint(p1) + 0x8000u;
        pk4[t >> 1] = __builtin_amdgcn_perm(u1, u0, 0x07060302);
      }
      af[mt] = __builtin_bit_cast(s8v, pk4);
    }
#pragma unroll
    for (int nt = 0; nt < 8; ++nt)
#pragma unroll
      for (int mt = 0; mt < 4; ++mt)
        acc[mt][nt] = __builtin_amdgcn_mfma_f32_16x16x32_bf16(af[mt], bfr[nt], acc[mt][nt], 0, 0, 0);
#pragma unroll
    for (int mt = 0; mt < 4; ++mt)
      accL[mt] = __builtin_amdgcn_mfma_f32_16x16x32_bf16(af[mt], ones, accL[mt], 0, 0, 0);

    Ec0 = En0; Ec1 = En1; Fc0 = Fn0; Fc1 = Fn1;
  }

  float* hsum = (float*)smem;
  float* l_red = (float*)(smem + 32768);
#pragma unroll
  for (int t = 0; t < 4; ++t)
    *(f4v*)(hsum + tid * 16 + t * 4) = (f4v){0.f, 0.f, 0.f, 0.f};
  if (tid < 64) l_red[tid] = 0.f;
  __syncthreads();

#pragma unroll
  for (int mt = 0; mt < 4; ++mt) {
    if (lcol == 0) {
#pragma unroll
      for (int r = 0; r < 4; ++r)
        atomicAdd(&l_red[16 * mt + (quad << 2) + r], accL[mt][r]);
    }
#pragma unroll
    for (int nt = 0; nt < 8; ++nt)
#pragma unroll
      for (int r = 0; r < 4; ++r) {
        int row = 16 * mt + (quad << 2) + r;
        int f = (nt << 4) + lcol;
        int fx = (f + (quad << 3)) & 127;
        atomicAdd(&hsum[(row << 7) + fx], acc[mt][nt][r]);
      }
  }
  __syncthreads();

  {
    int r = tid >> 3;
    int f0 = (tid & 7) << 4;
    int off = ((r >> 2) & 3) << 3;
    float il = 1.0f / l_red[r];
    size_t o = (((size_t)b * NN + i0 + r) << 7) + f0;
#pragma unroll
    for (int t = 0; t < 4; ++t) {
      int fx = (f0 + 4 * t + off) & 127;
      f4v v = *(const f4v*)(hsum + (r << 7) + fx);
      f4v ov;
#pragma unroll
      for (int e = 0; e < 4; ++e) {
        float x = v[e] * il;
        ov[e] = x > 0.f ? x : (__expf(x) - 1.f);
      }
      *(f4v*)(out + o + 4 * t) = ov;
    }
  }
}

extern "C" void kernel_launch(void* const* d_in, const int* in_sizes, int n_in,
                              void* d_out, int out_size, void* d_ws, size_t ws_size,
                              hipStream_t stream) {
  const float* h = (const float*)d_in[0];
  const float* W = (const float*)d_in[1];
  const float* a = (const float*)d_in[2];
  float* out = (float*)d_out;
  unsigned char* ws = (unsigned char*)d_ws;

  unsigned short* WhTt = (unsigned short*)ws;             // 4 MB tiled bf16
  float* s1g = (float*)(ws + 4194304);                    // 64 KB
  float* Eg  = (float*)(ws + 4259840);                    // 64 KB
  float* Fg  = (float*)(ws + 4325376);                    // 64 KB
  unsigned short* pO = (unsigned short*)(ws + 4390912);   // 33.6 MB bf16
  float* pl = (float*)(ws + 37945344);                    // 512 KB
  const size_t NEED_SPLIT = 38469632;
  const size_t NEED_MONO = 4390912;
  if (ws_size < NEED_MONO) return;  // clean absmax-fail => ws too small

  hipLaunchKernelGGL(k1_gemm, dim3(256), dim3(256), 0, stream,
                     h, W, a, WhTt, s1g, Eg, Fg);
  if (ws_size >= NEED_SPLIT) {
    hipLaunchKernelGGL(k3_v5, dim3(512), dim3(256), 0, stream,
                       WhTt, s1g, Eg, Fg, pO, pl);
    hipLaunchKernelGGL(k4_comb, dim3(1024), dim3(256), 0, stream,
                       pO, pl, out);
  } else {
    hipLaunchKernelGGL(k3_mono, dim3(256), dim3(512), 0, stream,
                       WhTt, s1g, Eg, Fg, out);
  }
}

// Round 12
// 96.364 us; speedup vs baseline: 1.0431x; 1.0184x over previous
//
#include <hip/hip_runtime.h>
#include <hip/hip_bf16.h>

// GraphAttentionLayer on MI355X. fp32 I/O, bf16 MFMA internally.
// e = LR(s1_i + s2_j), softmax_j, out = elu(attn @ Wh).
// Scale-free scores: q_ij = max(E_j, r_i*F_j); E=exp(s2-8), F=exp(a(s2-8)),
//   r_i = exp((a-1)(s1_i+8));  O_i = sum_j q Wh / sum_j q.
// K1: Wh MFMA -> tiled WhT [b][c:16][oct:32][f:128][jo:8] bf16 + s1,E,F.
// K3-v5 (R9 base, 97.3us best) + R12: SUPER-STEP staging — 16KB (2 ksteps)
//   per barrier, 8 barriers instead of 16; buffers 2x16KB + E/F = 36KB LDS
//   (2 blk/CU unchanged). Prefetch issued a full super-step ahead.
//   cvt_pk af-pack (R9). pO layout = R9 (R11 pairing was noise-neutral).
// K4: R9 exact — 1024 blocks x 256 thr (4 blk/CU), nt-pair per block.
// Dead ends (post-mortems): coop grid.sync (R4 ~220us); cross-block fused
//   combine (R6, device-scope release -> HBM); mono 1blk/CU (R8, 114us);
//   g-major XCD remap (R10, -3.2us: broke per-XCD B-panel locality).

#define ALPHA 0.2f
#define NN 4096
#define FD 128

typedef __attribute__((ext_vector_type(8))) short s8v;     // 8 x bf16 raw bits
typedef __attribute__((ext_vector_type(4))) float f4v;
typedef __attribute__((ext_vector_type(2))) unsigned int u2v;
typedef __attribute__((ext_vector_type(4))) unsigned int u4v;

__device__ __forceinline__ unsigned short f2bf(float x) {  // round-half-up
  return (unsigned short)((__float_as_uint(x) + 0x8000u) >> 16);
}

// ---------------- K1: Wh + tiled WhT + s1/E/F (unchanged) ----------------
__global__ __launch_bounds__(256, 4) void k1_gemm(
    const float* __restrict__ h, const float* __restrict__ W,
    const float* __restrict__ a,
    unsigned short* __restrict__ WhTt,      // tiled [4][16][32][128][8] bf16
    float* __restrict__ s1g, float* __restrict__ Eg, float* __restrict__ Fg)
{
  __shared__ __align__(16) unsigned char wls[32768];
  const int tid = threadIdx.x;
  const int b = blockIdx.x >> 6;
  const int j0 = (blockIdx.x & 63) << 6;

#pragma unroll
  for (int it = 0; it < 16; ++it) {          // W -> swizzled bf16 W^T in LDS
    int cidx = it * 256 + tid;
    int i = cidx >> 5;
    int f0 = (cidx & 31) << 2;
    f4v v = *(const f4v*)(W + (size_t)cidx * 4);
#pragma unroll
    for (int e = 0; e < 4; ++e) {
      int f = f0 + e;
      int byte = f * 256 + (((i >> 3) ^ (f & 15)) << 4) + ((i & 7) << 1);
      *(unsigned short*)(wls + byte) = f2bf(v[e]);
    }
  }
  __syncthreads();

  const int w = tid >> 6, lane = tid & 63;
  const int quad = lane >> 4, lcol = lane & 15;
  const int jrow = j0 + 16 * w + lcol;

  f4v acc[8];
#pragma unroll
  for (int nt = 0; nt < 8; ++nt) acc[nt] = (f4v){0.f, 0.f, 0.f, 0.f};

#pragma unroll
  for (int kk = 0; kk < 4; ++kk) {
    const float* hp = h + (((size_t)(b * NN + jrow)) << 7) + (kk << 5) + (quad << 3);
    f4v v0 = *(const f4v*)hp;
    f4v v1 = *(const f4v*)(hp + 4);
    s8v af;
#pragma unroll
    for (int e = 0; e < 4; ++e) { af[e] = (short)f2bf(v0[e]); af[4+e] = (short)f2bf(v1[e]); }
#pragma unroll
    for (int nt = 0; nt < 8; ++nt) {
      int f = 16 * nt + lcol;
      int slot = ((kk << 2) + quad) ^ (f & 15);
      s8v bfr = *(const s8v*)(wls + (f << 8) + (slot << 4));
      acc[nt] = __builtin_amdgcn_mfma_f32_16x16x32_bf16(af, bfr, acc[nt], 0, 0, 0);
    }
  }

  float s1v[4] = {0,0,0,0}, s2v[4] = {0,0,0,0};
#pragma unroll
  for (int nt = 0; nt < 8; ++nt) {
    float a1 = a[16 * nt + lcol];
    float a2 = a[128 + 16 * nt + lcol];
#pragma unroll
    for (int r = 0; r < 4; ++r) { s1v[r] += acc[nt][r] * a1; s2v[r] += acc[nt][r] * a2; }
  }
#pragma unroll
  for (int r = 0; r < 4; ++r)
#pragma unroll
    for (int d = 1; d < 16; d <<= 1) {
      s1v[r] += __shfl_xor(s1v[r], d, 64);
      s2v[r] += __shfl_xor(s2v[r], d, 64);
    }
  if (lcol == 0) {
    int jb = b * NN + j0 + 16 * w + (quad << 2);
    *(f4v*)(s1g + jb) = (f4v){s1v[0], s1v[1], s1v[2], s1v[3]};
    f4v Ee, Ff;
#pragma unroll
    for (int r = 0; r < 4; ++r) {
      float d = s2v[r] - 8.0f;              // <= 0 given |s2| <= 8
      Ee[r] = __expf(d);
      Ff[r] = __expf(ALPHA * d);
    }
    *(f4v*)(Eg + jb) = Ee;
    *(f4v*)(Fg + jb) = Ff;
  }

  {
    const int c = j0 >> 8;
    const int octb = ((j0 & 255) >> 3) + 2 * w + (quad >> 1);
    const int eoff = (quad & 1) << 2;
#pragma unroll
    for (int nt = 0; nt < 8; ++nt) {
      int f = 16 * nt + lcol;
      unsigned u0 = __float_as_uint(acc[nt][0]) + 0x8000u;
      unsigned u1 = __float_as_uint(acc[nt][1]) + 0x8000u;
      unsigned u2 = __float_as_uint(acc[nt][2]) + 0x8000u;
      unsigned u3 = __float_as_uint(acc[nt][3]) + 0x8000u;
      u2v pk;
      pk[0] = (u0 >> 16) | (u1 & 0xFFFF0000u);
      pk[1] = (u2 >> 16) | (u3 & 0xFFFF0000u);
      size_t off = ((((size_t)(b * 16 + c) * 32 + octb) * 128 + f) << 3) + eoff;
      *(u2v*)(WhTt + off) = pk;
    }
  }
}

// ---------------- K3-v5/R12: super-step staged, 64 rows/wave, 2 blk/CU ----
// grid 512 x 256 thr. blk: b=blk>>7, rgb=(blk>>3)&15, jq=blk&7 (R9 mapping).
// Wave w owns rows [rgb*256 + w*64, +64) (4 mt), j window [jq*512, +512).
// 8 super-steps x 64 j (2 ksteps each); 16KB staged per barrier.
// LDS: buf0 [0,16K) | buf1 [16K,32K) | E [32K,34K) | F [34K,36K).
__global__ __launch_bounds__(256, 2) void k3_v5(
    const unsigned short* __restrict__ WhTt,
    const float* __restrict__ s1g,
    const float* __restrict__ Eg,
    const float* __restrict__ Fg,
    unsigned short* __restrict__ pO,        // [512][32768] bf16 (R9 layout)
    float* __restrict__ pl)                 // [512][256] f32
{
  __shared__ __align__(16) unsigned char smem[36864];
  const int tid = threadIdx.x;
  const int w = tid >> 6, lane = tid & 63;
  const int quad = lane >> 4, lcol = lane & 15;
  const int blk = blockIdx.x;
  const int b = blk >> 7, rgb = (blk >> 3) & 15, jq = blk & 7;
  const int irow0 = rgb * 256 + w * 64;

  const unsigned short* whtb = WhTt + ((size_t)b << 19);
  const float* Egb = Eg + b * NN + (jq << 9);
  const float* Fgb = Fg + b * NN + (jq << 9);

  // E/F window: 512 + 512 floats, staged once
  if (tid < 128) {
    f4v v = *(const f4v*)(Egb + tid * 4);
    *(f4v*)(smem + 32768 + tid * 16) = v;
  } else {
    f4v v = *(const f4v*)(Fgb + (tid - 128) * 4);
    *(f4v*)(smem + 34816 + (tid - 128) * 16) = v;
  }

  float rr[4];
#pragma unroll
  for (int mt = 0; mt < 4; ++mt) {
    float x = s1g[b * NN + irow0 + 16 * mt + lcol] + 8.0f;
    rr[mt] = __expf((ALPHA - 1.0f) * x);    // <= 1 (x >= 0)
  }

  // super-tile for step S: 8 contiguous octets = 16KB (never crosses c-tile:
  // og0&31 in {0,8,16,24}, +8 <= 32)
  auto tilePtr = [&](int S) -> const unsigned short* {
    int og0 = (jq << 6) + (S << 3);
    return whtb + (((size_t)(og0 >> 5)) << 15) + ((og0 & 31) << 10);
  };
  {
    const unsigned short* tp = tilePtr(0);
#pragma unroll
    for (int i = 0; i < 4; ++i) {
      u4v t = *(const u4v*)(tp + i * 2048 + tid * 8);
      *(u4v*)(smem + i * 4096 + tid * 16) = t;     // linear 16KB copy -> buf0
    }
  }

  f4v acc[4][8], accL[4];
#pragma unroll
  for (int mt = 0; mt < 4; ++mt) {
    accL[mt] = (f4v){0.f, 0.f, 0.f, 0.f};
#pragma unroll
    for (int nt = 0; nt < 8; ++nt) acc[mt][nt] = (f4v){0.f, 0.f, 0.f, 0.f};
  }
  s8v ones;
  {
    short o = (lcol == 0) ? (short)0x3F80 : (short)0;
#pragma unroll
    for (int t = 0; t < 8; ++t) ones[t] = o;
  }

  const float* EFb = (const float*)(smem + 32768);

  for (int S = 0; S < 8; ++S) {             // 8 super-steps x 64 j
    __syncthreads();                        // buf[S&1] resident; prev reads done
    u4v tn0, tn1, tn2, tn3;
    if (S < 7) {
      const unsigned short* tp = tilePtr(S + 1);
      tn0 = *(const u4v*)(tp + tid * 8);    // reg prefetch, full super-tile
      tn1 = *(const u4v*)(tp + 2048 + tid * 8);
      tn2 = *(const u4v*)(tp + 4096 + tid * 8);
      tn3 = *(const u4v*)(tp + 6144 + tid * 8);
    }
    const unsigned char* buf = smem + ((S & 1) << 14);

#pragma unroll
    for (int ss = 0; ss < 2; ++ss) {        // 2 ksteps per super-step
      const int s = (S << 1) + ss;
      const int jloc = (s << 5) + (quad << 3);
      f4v Ea0 = *(const f4v*)(EFb + jloc);
      f4v Ea1 = *(const f4v*)(EFb + jloc + 4);
      f4v Fa0 = *(const f4v*)(EFb + 512 + jloc);
      f4v Fa1 = *(const f4v*)(EFb + 512 + jloc + 4);
      float Ev[8] = {Ea0[0], Ea0[1], Ea0[2], Ea0[3], Ea1[0], Ea1[1], Ea1[2], Ea1[3]};
      float Fv[8] = {Fa0[0], Fa0[1], Fa0[2], Fa0[3], Fa1[0], Fa1[1], Fa1[2], Fa1[3]};

      s8v bfr[8];
#pragma unroll
      for (int nt = 0; nt < 8; ++nt) {      // B-frag: kstep half ss, oct=quad
        int f = (nt << 4) + lcol;
        bfr[nt] = *(const s8v*)(buf + (ss << 13) + (quad << 11) + (f << 4));
      }

      s8v af[4];
#pragma unroll
      for (int mt = 0; mt < 4; ++mt) {      // q = max(E, r*F) -> bf16 pairs
        float R = rr[mt];
        u4v pk4;
#pragma unroll
        for (int t = 0; t < 8; t += 2) {
          float q0 = fmaxf(Ev[t], R * Fv[t]);
          float q1 = fmaxf(Ev[t + 1], R * Fv[t + 1]);
          unsigned pr;
          asm("v_cvt_pk_bf16_f32 %0, %1, %2" : "=v"(pr) : "v"(q0), "v"(q1));
          pk4[t >> 1] = pr;                 // low16=bf16(q0), high16=bf16(q1)
        }
        af[mt] = __builtin_bit_cast(s8v, pk4);
      }
#pragma unroll
      for (int nt = 0; nt < 8; ++nt)
#pragma unroll
        for (int mt = 0; mt < 4; ++mt)
          acc[mt][nt] = __builtin_amdgcn_mfma_f32_16x16x32_bf16(af[mt], bfr[nt], acc[mt][nt], 0, 0, 0);
#pragma unroll
      for (int mt = 0; mt < 4; ++mt)
        accL[mt] = __builtin_amdgcn_mfma_f32_16x16x32_bf16(af[mt], ones, accL[mt], 0, 0, 0);
    }

    if (S < 7) {                            // write prefetched super-tile S+1
      unsigned char* dst = smem + (((S + 1) & 1) << 14);
      *(u4v*)(dst + tid * 16) = tn0;
      *(u4v*)(dst + 4096 + tid * 16) = tn1;
      *(u4v*)(dst + 8192 + tid * 16) = tn2;
      *(u4v*)(dst + 12288 + tid * 16) = tn3;
    }
  }

  // partial stores, C-frag-native coalesced layout (R9-verified pair)
  if (lcol == 0) {
#pragma unroll
    for (int mt = 0; mt < 4; ++mt)
#pragma unroll
      for (int r = 0; r < 4; ++r)
        pl[(size_t)blk * 256 + w * 64 + 16 * mt + (quad << 2) + r] = accL[mt][r];
  }
  unsigned short* po = pO + (size_t)blk * 32768;
#pragma unroll
  for (int mt = 0; mt < 4; ++mt)
#pragma unroll
    for (int nt = 0; nt < 8; ++nt) {
      unsigned u0 = __float_as_uint(acc[mt][nt][0]) + 0x8000u;
      unsigned u1 = __float_as_uint(acc[mt][nt][1]) + 0x8000u;
      unsigned u2 = __float_as_uint(acc[mt][nt][2]) + 0x8000u;
      unsigned u3 = __float_as_uint(acc[mt][nt][3]) + 0x8000u;
      u2v pk;
      pk[0] = (u0 >> 16) | (u1 & 0xFFFF0000u);
      pk[1] = (u2 >> 16) | (u3 & 0xFFFF0000u);
      int off = ((((w << 2) + mt) << 3) + nt) * 256 + (lane << 2);
      *(u2v*)(po + off) = pk;
    }
}

// ---------------- K4: 8-way combine + normalize + ELU (R9 exact) ----------
// grid 1024 x 256 thr (4 blk/CU). b=blk>>8; chunk=(blk>>2)&63; sel=blk&3
// picks nt pair {2sel, 2sel+1}.
__global__ __launch_bounds__(256) void k4_comb(
    const unsigned short* __restrict__ pO, const float* __restrict__ pl,
    float* __restrict__ out)
{
  const int tid = threadIdx.x, blk = blockIdx.x;
  const int b = blk >> 8, chunk = (blk >> 2) & 63, sel = blk & 3;
  const int rgb = chunk >> 2, wv = chunk & 3;
  const int mt = tid >> 6, lane = tid & 63;
  const int quad = lane >> 4, lcol = lane & 15;
  const int kb = (b << 7) | (rgb << 3);     // k3 blk of q=0

  float il[4];
#pragma unroll
  for (int r = 0; r < 4; ++r) {
    int rowloc = wv * 64 + 16 * mt + (quad << 2) + r;
    float l = 0.f;
#pragma unroll
    for (int q = 0; q < 8; ++q) l += pl[(size_t)(kb + q) * 256 + rowloc];
    il[r] = 1.0f / l;
  }

  const size_t rowg0 = ((size_t)b * NN + rgb * 256 + wv * 64 + 16 * mt + (quad << 2));
#pragma unroll
  for (int ntl = 0; ntl < 2; ++ntl) {
    const int nt = (sel << 1) + ntl;
    const int off = ((((wv << 2) + mt) << 3) + nt) * 256 + (lane << 2);
    float s0 = 0.f, s1 = 0.f, s2 = 0.f, s3 = 0.f;
#pragma unroll
    for (int q = 0; q < 8; ++q) {
      u2v pk = *(const u2v*)(pO + (size_t)(kb + q) * 32768 + off);
      s0 += __uint_as_float(pk[0] << 16);
      s1 += __uint_as_float(pk[0] & 0xFFFF0000u);
      s2 += __uint_as_float(pk[1] << 16);
      s3 += __uint_as_float(pk[1] & 0xFFFF0000u);
    }
    float v[4] = {s0 * il[0], s1 * il[1], s2 * il[2], s3 * il[3]};
#pragma unroll
    for (int r = 0; r < 4; ++r) {
      float x = v[r];
      x = x > 0.f ? x : (__expf(x) - 1.f);  // elu
      out[(rowg0 + r) * 128 + (nt << 4) + lcol] = x;
    }
  }
}

// ---------------- K3-mono (fallback only; R8: 114us latency-bound) --------
__global__ __launch_bounds__(512, 2) void k3_mono(
    const unsigned short* __restrict__ WhTt,
    const float* __restrict__ s1g,
    const float* __restrict__ Eg,
    const float* __restrict__ Fg,
    float* __restrict__ out)
{
  __shared__ __align__(16) unsigned char smem[33024];
  const int tid = threadIdx.x;
  const int kp = tid >> 6, lane = tid & 63;
  const int quad = lane >> 4, lcol = lane & 15;
  const int b = (blockIdx.x & 7) >> 1;
  const int i0 = ((((blockIdx.x & 1) << 5) | (blockIdx.x >> 3))) << 6;
  const int c0 = (blockIdx.x >> 3) & 15;
  const int oct = (kp << 2) + quad;

  float Ar[4], Br[4];
#pragma unroll
  for (int mt = 0; mt < 4; ++mt) {
    float x = s1g[b * NN + i0 + 16 * mt + lcol] + 8.0f;
    float m = fmaxf(x, ALPHA * x);
    Ar[mt] = __expf(x - m);
    Br[mt] = __expf(ALPHA * x - m);
  }

  f4v acc[4][8], accL[4];
#pragma unroll
  for (int mt = 0; mt < 4; ++mt) {
    accL[mt] = (f4v){0.f, 0.f, 0.f, 0.f};
#pragma unroll
    for (int nt = 0; nt < 8; ++nt) acc[mt][nt] = (f4v){0.f, 0.f, 0.f, 0.f};
  }
  s8v ones;
  {
    short o = (lcol == 0) ? (short)0x3F80 : (short)0;
#pragma unroll
    for (int t = 0; t < 8; ++t) ones[t] = o;
  }

  const unsigned short* whtb = WhTt + ((size_t)b << 19);
  const float* Egb = Eg + b * NN;
  const float* Fgb = Fg + b * NN;
  const int jw = oct << 3;

  f4v Ec0 = *(const f4v*)(Egb + (c0 << 8) + jw);
  f4v Ec1 = *(const f4v*)(Egb + (c0 << 8) + jw + 4);
  f4v Fc0 = *(const f4v*)(Fgb + (c0 << 8) + jw);
  f4v Fc1 = *(const f4v*)(Fgb + (c0 << 8) + jw + 4);

  for (int cc = 0; cc < 16; ++cc) {
    const int c = (cc + c0) & 15;
    const unsigned short* tile = whtb + ((size_t)c << 15) + (oct << 10);
    s8v bfr[8];
#pragma unroll
    for (int nt = 0; nt < 8; ++nt)
      bfr[nt] = *(const s8v*)(tile + (((nt << 4) + lcol) << 3));

    f4v En0, En1, Fn0, Fn1;
    if (cc < 15) {
      int jg = (((cc + 1 + c0) & 15) << 8) + jw;
      En0 = *(const f4v*)(Egb + jg); En1 = *(const f4v*)(Egb + jg + 4);
      Fn0 = *(const f4v*)(Fgb + jg); Fn1 = *(const f4v*)(Fgb + jg + 4);
    }

    float Ev[8] = {Ec0[0], Ec0[1], Ec0[2], Ec0[3], Ec1[0], Ec1[1], Ec1[2], Ec1[3]};
    float Fv[8] = {Fc0[0], Fc0[1], Fc0[2], Fc0[3], Fc1[0], Fc1[1], Fc1[2], Fc1[3]};

    s8v af[4];
#pragma unroll
    for (int mt = 0; mt < 4; ++mt) {
      float A = Ar[mt], Bc = Br[mt];
      u4v pk4;
#pragma unroll
      for (int t = 0; t < 8; t += 2) {
        float p0 = fmaxf(A * Ev[t], Bc * Fv[t]);
        float p1 = fmaxf(A * Ev[t + 1], Bc * Fv[t + 1]);
        unsigned u0 = __float_as_uint(p0) + 0x8000u;
        unsigned u1 = __float_as_uint(p1) + 0x8000u;
        pk4[t >> 1] = __builtin_amdgcn_perm(u1, u0, 0x07060302);
      }
      af[mt] = __builtin_bit_cast(s8v, pk4);
    }
#pragma unroll
    for (int nt = 0; nt < 8; ++nt)
#pragma unroll
      for (int mt = 0; mt < 4; ++mt)
        acc[mt][nt] = __builtin_amdgcn_mfma_f32_16x16x32_bf16(af[mt], bfr[nt], acc[mt][nt], 0, 0, 0);
#pragma unroll
    for (int mt = 0; mt < 4; ++mt)
      accL[mt] = __builtin_amdgcn_mfma_f32_16x16x32_bf16(af[mt], ones, accL[mt], 0, 0, 0);

    Ec0 = En0; Ec1 = En1; Fc0 = Fn0; Fc1 = Fn1;
  }

  float* hsum = (float*)smem;
  float* l_red = (float*)(smem + 32768);
#pragma unroll
  for (int t = 0; t < 4; ++t)
    *(f4v*)(hsum + tid * 16 + t * 4) = (f4v){0.f, 0.f, 0.f, 0.f};
  if (tid < 64) l_red[tid] = 0.f;
  __syncthreads();

#pragma unroll
  for (int mt = 0; mt < 4; ++mt) {
    if (lcol == 0) {
#pragma unroll
      for (int r = 0; r < 4; ++r)
        atomicAdd(&l_red[16 * mt + (quad << 2) + r], accL[mt][r]);
    }
#pragma unroll
    for (int nt = 0; nt < 8; ++nt)
#pragma unroll
      for (int r = 0; r < 4; ++r) {
        int row = 16 * mt + (quad << 2) + r;
        int f = (nt << 4) + lcol;
        int fx = (f + (quad << 3)) & 127;
        atomicAdd(&hsum[(row << 7) + fx], acc[mt][nt][r]);
      }
  }
  __syncthreads();

  {
    int r = tid >> 3;
    int f0 = (tid & 7) << 4;
    int off = ((r >> 2) & 3) << 3;
    float il = 1.0f / l_red[r];
    size_t o = (((size_t)b * NN + i0 + r) << 7) + f0;
#pragma unroll
    for (int t = 0; t < 4; ++t) {
      int fx = (f0 + 4 * t + off) & 127;
      f4v v = *(const f4v*)(hsum + (r << 7) + fx);
      f4v ov;
#pragma unroll
      for (int e = 0; e < 4; ++e) {
        float x = v[e] * il;
        ov[e] = x > 0.f ? x : (__expf(x) - 1.f);
      }
      *(f4v*)(out + o + 4 * t) = ov;
    }
  }
}

extern "C" void kernel_launch(void* const* d_in, const int* in_sizes, int n_in,
                              void* d_out, int out_size, void* d_ws, size_t ws_size,
                              hipStream_t stream) {
  const float* h = (const float*)d_in[0];
  const float* W = (const float*)d_in[1];
  const float* a = (const float*)d_in[2];
  float* out = (float*)d_out;
  unsigned char* ws = (unsigned char*)d_ws;

  unsigned short* WhTt = (unsigned short*)ws;             // 4 MB tiled bf16
  float* s1g = (float*)(ws + 4194304);                    // 64 KB
  float* Eg  = (float*)(ws + 4259840);                    // 64 KB
  float* Fg  = (float*)(ws + 4325376);                    // 64 KB
  unsigned short* pO = (unsigned short*)(ws + 4390912);   // 33.6 MB bf16
  float* pl = (float*)(ws + 37945344);                    // 512 KB
  const size_t NEED_SPLIT = 38469632;
  const size_t NEED_MONO = 4390912;
  if (ws_size < NEED_MONO) return;  // clean absmax-fail => ws too small

  hipLaunchKernelGGL(k1_gemm, dim3(256), dim3(256), 0, stream,
                     h, W, a, WhTt, s1g, Eg, Fg);
  if (ws_size >= NEED_SPLIT) {
    hipLaunchKernelGGL(k3_v5, dim3(512), dim3(256), 0, stream,
                       WhTt, s1g, Eg, Fg, pO, pl);
    hipLaunchKernelGGL(k4_comb, dim3(1024), dim3(256), 0, stream,
                       pO, pl, out);
  } else {
    hipLaunchKernelGGL(k3_mono, dim3(256), dim3(512), 0, stream,
                       WhTt, s1g, Eg, Fg, out);
  }
}